// Round 16
// baseline (365.680 us; speedup 1.0000x reference)
//
#include <hip/hip_runtime.h>
#include <hip/hip_bf16.h>

// ReEig = 0.5*(X + eps*I + |X - eps*I|);  |B| = B*sign(B);  sign via Newton-Schulz,
// symmetrization folded into MFMA double products (X <- XW' + W'X, W'=W/2).
// r15 = r14's proven numerics (G8+P4, 1-pass window [5,10), mu at it-1, trace
// gate) re-tiled on mfma_f32_32x32x16_bf16: HALF the MFMA instructions (1296
// vs 2592/matrix), ~15% faster matrix pipe (2495 vs 2176 TF), freed issue
// slots for the co-issued VALU. Layout safety: all products are of commuting
// symmetric matrices, so shared A/B k-relabelings cancel and row/col transposes
// are no-ops; D-layout (col=lane&31, row=(reg&3)+8(reg>>2)+4(lane>>5)) is
// HW-verified (m74/m101). Trace gate + fp32 fallback net retained.

typedef float  f32x16 __attribute__((ext_vector_type(16)));
typedef short  short8 __attribute__((ext_vector_type(8)));

constexpr float EPS_  = 1e-4f;
constexpr int   ITERS = 12;   // 0-7 grow (2.25x), 8-11 polish (1.5x)
constexpr int   GROW  = 8;
constexpr int   ONE_LO = 5, ONE_HI = 10;  // 1-pass bf16 window [5,10)
constexpr int   LDH   = 72;               // bf16 plane row stride (shorts)
constexpr int   PLANE = 64 * LDH;         // 9216 B per plane
constexpr int   WAVE_S = 2 * PLANE;       // hi + lo planes per wave

struct Frag { short8 hi, lo; };

__device__ __forceinline__ unsigned short bf_hi(float x) {
    return __builtin_bit_cast(unsigned short, __float2bfloat16(x));  // RNE
}
__device__ __forceinline__ float bf_f(unsigned short h) {
    return __uint_as_float((unsigned)h << 16);
}
__device__ __forceinline__ Frag pack3(const float e[8]) {
    Frag f;
#pragma unroll
    for (int j = 0; j < 8; ++j) {
        const unsigned short h = bf_hi(e[j]);
        f.hi[j] = (short)h;
        f.lo[j] = (short)bf_hi(e[j] - bf_f(h));   // exact residual (Dekker)
    }
    return f;
}
__device__ __forceinline__ f32x16 mfma_bf(short8 a, short8 b, f32x16 c) {
    return __builtin_amdgcn_mfma_f32_32x32x16_bf16(a, b, c, 0, 0, 0);
}
__device__ __forceinline__ f32x16 mfma3(const Frag& a, const Frag& b, f32x16 c) {
    c = mfma_bf(a.hi, b.hi, c);
    c = mfma_bf(a.hi, b.lo, c);
    c = mfma_bf(a.lo, b.hi, c);
    return c;
}

// ---- bf16 hi/lo plane staging, swizzle col ^= row&24 ----
// D-tile (i,j) element (p,q): p = 32i + (r&3)+8(r>>2)+4hw, q = 32j+lo5.
// Transposed store: plane[q][p], per reg-quad rq a 4-short (uint2) chunk.
__device__ __forceinline__ void stHL32(short* Hhi, short* Hlo, bool lo,
                                       int lo5, int hw, int i, int j,
                                       const f32x16& v) {
    const int row  = 32 * j + lo5;
    const int rsw  = row & 24;
    const int idx0 = row * LDH;
#pragma unroll
    for (int rq = 0; rq < 4; ++rq) {
        const int cb = (32 * i + 8 * rq + 4 * hw) ^ rsw;
        const float a0 = v[4*rq+0], a1 = v[4*rq+1], a2 = v[4*rq+2], a3 = v[4*rq+3];
        const unsigned short h0 = bf_hi(a0), h1 = bf_hi(a1);
        const unsigned short h2 = bf_hi(a2), h3 = bf_hi(a3);
        uint2 u;
        u.x = ((unsigned)h1 << 16) | h0;
        u.y = ((unsigned)h3 << 16) | h2;
        *reinterpret_cast<uint2*>(Hhi + idx0 + cb) = u;
        if (lo) {
            const unsigned short l0 = bf_hi(a0 - bf_f(h0)), l1 = bf_hi(a1 - bf_f(h1));
            const unsigned short l2 = bf_hi(a2 - bf_f(h2)), l3 = bf_hi(a3 - bf_f(h3));
            uint2 w;
            w.x = ((unsigned)l1 << 16) | l0;
            w.y = ((unsigned)l3 << 16) | l2;
            *reinterpret_cast<uint2*>(Hlo + idx0 + cb) = w;
        }
    }
}
// frag read: M[32i+lo5][16s+8hw+j], j=0..7 -> one b128 per plane
__device__ __forceinline__ short8 rdP32(const short* H, int lo5, int hw, int i, int s) {
    const int row = 32 * i + lo5;
    const int col = (16 * s + 8 * hw) ^ (row & 24);
    return *reinterpret_cast<const short8*>(H + row * LDH + col);
}
__device__ __forceinline__ void load_row8_32(const float* src, int lo5, int hw,
                                             int i, int s, float e[8]) {
    const int row = 32 * i + lo5;
    const int c0  = 16 * s + 8 * hw;
    const float* rp = src + row * 64 + c0;
    const float4 a = *reinterpret_cast<const float4*>(rp);
    const float4 b = *reinterpret_cast<const float4*>(rp + 4);
    e[0]=a.x; e[1]=a.y; e[2]=a.z; e[3]=a.w;
    e[4]=b.x; e[5]=b.y; e[6]=b.z; e[7]=b.w;
    const int dj = row - c0;
#pragma unroll
    for (int j = 0; j < 8; ++j) if (j == dj) e[j] -= EPS_;
}
__device__ __forceinline__ void zeroD(f32x16 D[2][2]) {
#pragma unroll
    for (int i = 0; i < 2; ++i)
#pragma unroll
    for (int j = 0; j < 2; ++j)
#pragma unroll
    for (int r = 0; r < 16; ++r) D[i][j][r] = 0.f;
}

__global__ __launch_bounds__(256, 2) void reeig_mx(const float* __restrict__ in,
                                                   float* __restrict__ out,
                                                   int* __restrict__ flags) {
    __shared__ __align__(16) short lds4[4 * WAVE_S];   // 73728 B/block

    const int lane = threadIdx.x & 63;
    const int wave = threadIdx.x >> 6;
    const int lo5  = lane & 31;
    const int hw   = lane >> 5;
    short* Hhi = &lds4[wave * WAVE_S];
    short* Hlo = Hhi + PLANE;

    // diagonal ownership: lane holds diag elements of tile (i,i) iff dvalid,
    // at reg index rdiag (static-unrolled selects only; rule #20)
    const int  vd     = lo5 - 4 * hw;
    const bool dvalid = (vd >= 0) && ((vd & 4) == 0);
    const int  rdiag  = dvalid ? ((vd & 3) + 4 * (vd >> 3)) : 0;

    const long mat = (long)blockIdx.x * 4 + wave;
    const float* __restrict__ src = in  + mat * 4096;
    float*       __restrict__ dst = out + mat * 4096;

    // ---- load B = X - eps*I as UNSCALED frags; Frobenius norm ----
    Frag xf[4][2];   // [k-block s][tile i]
    float fro = 0.f;
#pragma unroll
    for (int s = 0; s < 4; ++s)
#pragma unroll
    for (int i = 0; i < 2; ++i) {
        float e[8];
        load_row8_32(src, lo5, hw, i, s, e);
#pragma unroll
        for (int j = 0; j < 8; ++j) fro = fmaf(e[j], e[j], fro);
        xf[s][i] = pack3(e);
    }
#pragma unroll
    for (int m = 1; m < 64; m <<= 1) fro += __shfl_xor(fro, m, 64);
    const float invF = rsqrtf(fro);

    float s_acc = 0.f;   // ||B^2||_F^2 from it-0 gram -> mu at it-1
    f32x16 D[2][2];

    for (int it = 0; it < ITERS; ++it) {
        const bool three  = (it < ONE_LO) || (it >= ONE_HI);
        const bool g1     = !three || (it == ONE_HI);
        const bool xlo0   = (it == ONE_HI);
        const bool xlo_st = three && (it != ONE_LO - 1);
        float c1 = (it < GROW) ? 2.25f    : 1.5f;
        float c3 = (it < GROW) ? -1.6875f : -0.5f;
        if (it == 0) { c1 *= invF; c3 *= invF * invF * invF; }
        if (it == 1) {
            float s = s_acc;
#pragma unroll
            for (int m = 1; m < 64; m <<= 1) s += __shfl_xor(s, m, 64);
            const float mu = sqrtf(sqrtf(s)) * invF;
            const float xm = fminf(mu, 0.6666667f);
            const float fv = 2.25f * xm - 1.6875f * xm * xm * xm;
            const float im = 0.98f / fv;
            c1 *= im; c3 *= im * im * im;
        }
        c1 *= 0.5f; c3 *= 0.5f;   // W' = W/2

        // ---- gram: D = X^2 ----
        zeroD(D);
#pragma unroll
        for (int s = 0; s < 4; ++s)
#pragma unroll
        for (int i = 0; i < 2; ++i)
#pragma unroll
        for (int j = 0; j < 2; ++j) {
            if (g1) D[i][j] = mfma_bf(xf[s][i].hi, xf[s][j].hi, D[i][j]);
            else    D[i][j] = mfma3 (xf[s][i],    xf[s][j],    D[i][j]);
        }
        if (it == 0) {
#pragma unroll
            for (int i = 0; i < 2; ++i)
#pragma unroll
            for (int j = 0; j < 2; ++j)
#pragma unroll
            for (int r = 0; r < 16; ++r) s_acc = fmaf(D[i][j][r], D[i][j][r], s_acc);
        }

        // ---- store W' = 0.5*(c1*I + c3*X^2), transposed (== W') ----
#pragma unroll
        for (int i = 0; i < 2; ++i)
#pragma unroll
        for (int j = 0; j < 2; ++j) {
            f32x16 v;
#pragma unroll
            for (int r = 0; r < 16; ++r) {
                float val = c3 * D[i][j][r];
                if (i == j && dvalid && r == rdiag) val += c1;
                v[r] = val;
            }
            stHL32(Hhi, Hlo, three, lo5, hw, i, j, v);
        }

        // ---- mm2: D = X*W' + W'*X ----
        zeroD(D);
#pragma unroll
        for (int s = 0; s < 4; ++s) {
            Frag wf[2];
#pragma unroll
            for (int t = 0; t < 2; ++t) {
                wf[t].hi = rdP32(Hhi, lo5, hw, t, s);
                wf[t].lo = three ? rdP32(Hlo, lo5, hw, t, s) : short8{0,0,0,0,0,0,0,0};
            }
#pragma unroll
            for (int i = 0; i < 2; ++i)
#pragma unroll
            for (int j = 0; j < 2; ++j) {
                if (three) {
                    D[i][j] = mfma_bf(xf[s][i].hi, wf[j].hi, D[i][j]);
                    D[i][j] = mfma_bf(xf[s][i].hi, wf[j].lo, D[i][j]);
                    if (!xlo0) D[i][j] = mfma_bf(xf[s][i].lo, wf[j].hi, D[i][j]);
                    D[i][j] = mfma_bf(wf[i].hi, xf[s][j].hi, D[i][j]);
                    D[i][j] = mfma_bf(wf[i].lo, xf[s][j].hi, D[i][j]);
                    if (!xlo0) D[i][j] = mfma_bf(wf[i].hi, xf[s][j].lo, D[i][j]);
                } else {
                    D[i][j] = mfma_bf(xf[s][i].hi, wf[j].hi, D[i][j]);
                    D[i][j] = mfma_bf(wf[i].hi, xf[s][j].hi, D[i][j]);
                }
            }
        }

        // ---- store X_new (transposed), read back fragments ----
#pragma unroll
        for (int i = 0; i < 2; ++i)
#pragma unroll
        for (int j = 0; j < 2; ++j) stHL32(Hhi, Hlo, xlo_st, lo5, hw, i, j, D[i][j]);
#pragma unroll
        for (int s = 0; s < 4; ++s)
#pragma unroll
        for (int i = 0; i < 2; ++i) {
            xf[s][i].hi = rdP32(Hhi, lo5, hw, i, s);
            xf[s][i].lo = xlo_st ? rdP32(Hlo, lo5, hw, i, s) : short8{0,0,0,0,0,0,0,0};
        }
    }
    // xf = frags of S = sign(B)

    // ---- validation: trace gate tr(S^2 - I) in (-4.5, 0.9), NaN-safe ----
    zeroD(D);
#pragma unroll
    for (int s = 0; s < 4; ++s)
#pragma unroll
    for (int i = 0; i < 2; ++i)
#pragma unroll
    for (int j = 0; j < 2; ++j) D[i][j] = mfma_bf(xf[s][i].hi, xf[s][j].hi, D[i][j]);
    float trc = 0.f;
    if (dvalid) {
#pragma unroll
        for (int r = 0; r < 16; ++r)
            if (r == rdiag) trc = D[0][0][r] + D[1][1][r];   // static index
    }
#pragma unroll
    for (int m = 1; m < 64; m <<= 1) trc += __shfl_xor(trc, m, 64);
    const float trdev = trc - 64.f;
    const bool  bad   = !(trdev > -4.5f && trdev < 0.9f);

    // ---- epilogue: D = B*S + S*B (symmetrized double product) ----
    zeroD(D);
#pragma unroll
    for (int s = 0; s < 4; ++s) {
        Frag b4[2];
#pragma unroll
        for (int t = 0; t < 2; ++t) {
            float e[8]; load_row8_32(src, lo5, hw, t, s, e); b4[t] = pack3(e);
        }
#pragma unroll
        for (int i = 0; i < 2; ++i)
#pragma unroll
        for (int j = 0; j < 2; ++j) {
            D[i][j] = mfma3(b4[i], xf[s][j], D[i][j]);
            D[i][j] = mfma3(xf[s][i], b4[j], D[i][j]);
        }
    }

    // out = 0.25*(BS+SB) + 0.5*B + eps*I
#pragma unroll
    for (int i = 0; i < 2; ++i)
#pragma unroll
    for (int j = 0; j < 2; ++j)
#pragma unroll
    for (int r = 0; r < 16; ++r) {
        const int p = 32 * i + (r & 3) + 8 * (r >> 2) + 4 * hw;
        const int q = 32 * j + lo5;
        const float bval = src[p * 64 + q] - ((p == q) ? EPS_ : 0.f);
        dst[p * 64 + q] = 0.25f * D[i][j][r] + 0.5f * bval + ((p == q) ? EPS_ : 0.f);
    }

    if (lane == 0) flags[mat] = bad ? 1 : 0;
}

// ------------------------ fp32 fallback (known good) ------------------------
constexpr int FB_LD = 68;

__device__ __forceinline__ void fb_mm64(const float* __restrict__ A,
                                        const float* __restrict__ Bm,
                                        int ti, int tj, float acc[4][4]) {
#pragma unroll
    for (int r = 0; r < 4; ++r)
#pragma unroll
        for (int cc = 0; cc < 4; ++cc) acc[r][cc] = 0.f;
#pragma unroll 4
    for (int k = 0; k < 64; ++k) {
        const float4 a = *reinterpret_cast<const float4*>(&A [k * FB_LD + 4 * ti]);
        const float4 b = *reinterpret_cast<const float4*>(&Bm[k * FB_LD + 4 * tj]);
        const float ar[4] = {a.x, a.y, a.z, a.w};
        const float br[4] = {b.x, b.y, b.z, b.w};
#pragma unroll
        for (int r = 0; r < 4; ++r)
#pragma unroll
            for (int cc = 0; cc < 4; ++cc)
                acc[r][cc] = fmaf(ar[r], br[cc], acc[r][cc]);
    }
}

__global__ __launch_bounds__(256) void reeig_fb(const float* __restrict__ in,
                                                float* __restrict__ out,
                                                const int* __restrict__ flags) {
    if (flags && flags[blockIdx.x] == 0) return;

    __shared__ __align__(16) float Bs[64 * FB_LD];
    __shared__ __align__(16) float Xs[64 * FB_LD];
    __shared__ __align__(16) float Ws[64 * FB_LD];
    __shared__ float red[4];

    const int tid = threadIdx.x;
    const int tj  = tid & 15;
    const int ti  = tid >> 4;
    const size_t base = (size_t)blockIdx.x * 4096;
    const float* __restrict__ src = in + base;
    float* __restrict__ dst = out + base;

    float4 v4[4];
    float frob = 0.f;
#pragma unroll
    for (int q = 0; q < 4; ++q) {
        const int idx4 = tid + 256 * q;
        const int lin  = idx4 << 2;
        const int r    = lin >> 6;
        const int c    = lin & 63;
        float4 v = reinterpret_cast<const float4*>(src)[idx4];
        const int d = r - c;
        v.x -= (d == 0) ? EPS_ : 0.f;
        v.y -= (d == 1) ? EPS_ : 0.f;
        v.z -= (d == 2) ? EPS_ : 0.f;
        v.w -= (d == 3) ? EPS_ : 0.f;
        v4[q] = v;
        frob += v.x * v.x + v.y * v.y + v.z * v.z + v.w * v.w;
        *reinterpret_cast<float4*>(&Bs[r * FB_LD + c]) = v;
    }
#pragma unroll
    for (int off = 32; off > 0; off >>= 1) frob += __shfl_down(frob, off);
    if ((tid & 63) == 0) red[tid >> 6] = frob;
    __syncthreads();
    const float tot = red[0] + red[1] + red[2] + red[3];
    const float inv = (tot > 0.f) ? rsqrtf(tot) : 0.f;

#pragma unroll
    for (int q = 0; q < 4; ++q) {
        const int idx4 = tid + 256 * q;
        const int lin  = idx4 << 2;
        const int r    = lin >> 6;
        const int c    = lin & 63;
        float4 v = v4[q];
        v.x *= inv; v.y *= inv; v.z *= inv; v.w *= inv;
        *reinterpret_cast<float4*>(&Xs[r * FB_LD + c]) = v;
    }
    __syncthreads();

    float acc[4][4];
    for (int it = 0; it < 14; ++it) {
        const bool  g  = (it < 9);
        const float c1 = g ? 2.25f    : 1.5f;
        const float c3 = g ? -1.6875f : -0.5f;

        fb_mm64(Xs, Xs, ti, tj, acc);
#pragma unroll
        for (int r = 0; r < 4; ++r) {
            const int i = 4 * ti + r;
            float4 w;
            w.x = c3 * acc[r][0] + ((i == 4 * tj + 0) ? c1 : 0.f);
            w.y = c3 * acc[r][1] + ((i == 4 * tj + 1) ? c1 : 0.f);
            w.z = c3 * acc[r][2] + ((i == 4 * tj + 2) ? c1 : 0.f);
            w.w = c3 * acc[r][3] + ((i == 4 * tj + 3) ? c1 : 0.f);
            *reinterpret_cast<float4*>(&Ws[i * FB_LD + 4 * tj]) = w;
        }
        __syncthreads();

        fb_mm64(Xs, Ws, ti, tj, acc);
        __syncthreads();
#pragma unroll
        for (int r = 0; r < 4; ++r) {
            const int i = 4 * ti + r;
            float4 x;
            x.x = acc[r][0]; x.y = acc[r][1]; x.z = acc[r][2]; x.w = acc[r][3];
            *reinterpret_cast<float4*>(&Xs[i * FB_LD + 4 * tj]) = x;
        }
        __syncthreads();
    }

    fb_mm64(Bs, Xs, ti, tj, acc);
#pragma unroll
    for (int r = 0; r < 4; ++r) {
        const int i = 4 * ti + r;
        float4 o;
        o.x = 0.5f * (acc[r][0] + Bs[i * FB_LD + 4 * tj + 0]) + ((i == 4 * tj + 0) ? EPS_ : 0.f);
        o.y = 0.5f * (acc[r][1] + Bs[i * FB_LD + 4 * tj + 1]) + ((i == 4 * tj + 1) ? EPS_ : 0.f);
        o.z = 0.5f * (acc[r][2] + Bs[i * FB_LD + 4 * tj + 2]) + ((i == 4 * tj + 2) ? EPS_ : 0.f);
        o.w = 0.5f * (acc[r][3] + Bs[i * FB_LD + 4 * tj + 3]) + ((i == 4 * tj + 3) ? EPS_ : 0.f);
        *reinterpret_cast<float4*>(&dst[i * 64 + 4 * tj]) = o;
    }
}

extern "C" void kernel_launch(void* const* d_in, const int* in_sizes, int n_in,
                              void* d_out, int out_size, void* d_ws, size_t ws_size,
                              hipStream_t stream) {
    const float* X = (const float*)d_in[0];
    float* O = (float*)d_out;
    const int nmat = in_sizes[0] / 4096;   // 8192
    if (ws_size >= (size_t)nmat * sizeof(int)) {
        int* flags = (int*)d_ws;
        reeig_mx<<<nmat / 4, 256, 0, stream>>>(X, O, flags);
        reeig_fb<<<nmat, 256, 0, stream>>>(X, O, flags);
    } else {
        reeig_fb<<<nmat, 256, 0, stream>>>(X, O, nullptr);
    }
}

// Round 17
// 333.669 us; speedup vs baseline: 1.0959x; 1.0959x over previous
//
#include <hip/hip_runtime.h>
#include <hip/hip_bf16.h>

// ReEig = 0.5*(X + eps*I + |X - eps*I|);  |B| = B*sign(B);  sign via Newton-Schulz,
// symmetrization folded into MFMA double products (X <- XW' + W'X, W'=W/2).
// r16 = REVERT to r14 (proven 334.9us, absmax 0.031): 16x16x32 tiling.
// r15's 32x32 retile passed numerically but regressed (365.7us): per-instr
// cycle cost (8 vs ~5 cyc) means halving instructions bought only ~17% pipe
// time, and the strided D-layout reg-quads fragmented the transposed store
// (bank conflicts 2.9e7->3.88e7). G8+P4 = 12 iters, 1-pass window [5,10),
// mu-scaling at it-1, trace gate tr(S^2-I) in (-4.5,0.9), fp32 fallback net.

typedef float  f32x4  __attribute__((ext_vector_type(4)));
typedef short  short8 __attribute__((ext_vector_type(8)));

constexpr float EPS_  = 1e-4f;
constexpr int   ITERS = 12;   // 0-7 grow (2.25x), 8-11 polish (1.5x)
constexpr int   GROW  = 8;
constexpr int   ONE_LO = 5, ONE_HI = 10;  // 1-pass bf16 window [5,10)
constexpr int   LDH   = 72;               // bf16 plane row stride (shorts)
constexpr int   PLANE = 64 * LDH;         // 9216 B per plane
constexpr int   WAVE_S = 2 * PLANE;       // hi + lo planes per wave

struct Frag { short8 hi, lo; };

__device__ __forceinline__ unsigned short bf_hi(float x) {
    return __builtin_bit_cast(unsigned short, __float2bfloat16(x));  // RNE
}
__device__ __forceinline__ float bf_f(unsigned short h) {
    return __uint_as_float((unsigned)h << 16);
}
__device__ __forceinline__ Frag pack3(const float e[8]) {
    Frag f;
#pragma unroll
    for (int j = 0; j < 8; ++j) {
        const unsigned short h = bf_hi(e[j]);
        f.hi[j] = (short)h;
        f.lo[j] = (short)bf_hi(e[j] - bf_f(h));   // exact residual (Dekker)
    }
    return f;
}
__device__ __forceinline__ f32x4 mfma_bf(short8 a, short8 b, f32x4 c) {
    return __builtin_amdgcn_mfma_f32_16x16x32_bf16(a, b, c, 0, 0, 0);
}
__device__ __forceinline__ f32x4 mfma3(const Frag& a, const Frag& b, f32x4 c) {
    c = mfma_bf(a.hi, b.hi, c);
    c = mfma_bf(a.hi, b.lo, c);
    c = mfma_bf(a.lo, b.hi, c);
    return c;
}

// ---- bf16 hi/lo plane staging, swizzle col ^= row&24 (8-short granules) ----
__device__ __forceinline__ void stHL(short* Hhi, short* Hlo, bool lo,
                                     int c, int h4, int i, int j, f32x4 v) {
    const int row = 16 * j + c;
    const int col = (16 * i + 4 * h4) ^ (row & 24);
    const int idx = row * LDH + col;
    unsigned short h0 = bf_hi(v[0]), h1 = bf_hi(v[1]), h2 = bf_hi(v[2]), h3 = bf_hi(v[3]);
    uint2 u;
    u.x = ((unsigned)h1 << 16) | h0;
    u.y = ((unsigned)h3 << 16) | h2;
    *reinterpret_cast<uint2*>(Hhi + idx) = u;
    if (lo) {
        unsigned short l0 = bf_hi(v[0] - bf_f(h0)), l1 = bf_hi(v[1] - bf_f(h1));
        unsigned short l2 = bf_hi(v[2] - bf_f(h2)), l3 = bf_hi(v[3] - bf_f(h3));
        uint2 w;
        w.x = ((unsigned)l1 << 16) | l0;
        w.y = ((unsigned)l3 << 16) | l2;
        *reinterpret_cast<uint2*>(Hlo + idx) = w;
    }
}
__device__ __forceinline__ short8 rdP(const short* H, int c, int h4, int t, int S) {
    const int row = 16 * t + c;
    const int col = (32 * S + 8 * h4) ^ (row & 24);
    return *reinterpret_cast<const short8*>(H + row * LDH + col);
}
__device__ __forceinline__ void load_row8(const float* src, int c, int h4,
                                          int t, int S, float e[8]) {
    const int row = 16 * t + c;
    const float* rp = src + row * 64 + 32 * S + 8 * h4;
    const float4 a = *reinterpret_cast<const float4*>(rp);
    const float4 b = *reinterpret_cast<const float4*>(rp + 4);
    e[0]=a.x; e[1]=a.y; e[2]=a.z; e[3]=a.w;
    e[4]=b.x; e[5]=b.y; e[6]=b.z; e[7]=b.w;
    const int dj = row - (32 * S + 8 * h4);
#pragma unroll
    for (int j = 0; j < 8; ++j) if (j == dj) e[j] -= EPS_;
}
__device__ __forceinline__ void zeroD(f32x4 D[4][4]) {
#pragma unroll
    for (int i = 0; i < 4; ++i)
#pragma unroll
    for (int j = 0; j < 4; ++j) D[i][j] = f32x4{0.f, 0.f, 0.f, 0.f};
}

__global__ __launch_bounds__(256, 2) void reeig_mx(const float* __restrict__ in,
                                                   float* __restrict__ out,
                                                   int* __restrict__ flags) {
    __shared__ __align__(16) short lds4[4 * WAVE_S];   // 73728 B/block

    const int lane = threadIdx.x & 63;
    const int wave = threadIdx.x >> 6;
    const int c    = lane & 15;
    const int h4   = lane >> 4;
    short* Hhi = &lds4[wave * WAVE_S];
    short* Hlo = Hhi + PLANE;

    const long mat = (long)blockIdx.x * 4 + wave;
    const float* __restrict__ src = in  + mat * 4096;
    float*       __restrict__ dst = out + mat * 4096;

    // ---- load B = X - eps*I as UNSCALED frags; Frobenius norm ----
    Frag xf[2][4];
    float fro = 0.f;
#pragma unroll
    for (int S = 0; S < 2; ++S)
#pragma unroll
    for (int t = 0; t < 4; ++t) {
        float e[8];
        load_row8(src, c, h4, t, S, e);
#pragma unroll
        for (int j = 0; j < 8; ++j) fro = fmaf(e[j], e[j], fro);
        xf[S][t] = pack3(e);
    }
#pragma unroll
    for (int m = 1; m < 64; m <<= 1) fro += __shfl_xor(fro, m, 64);
    const float invF = rsqrtf(fro);

    float s_acc = 0.f;   // ||B^2||_F^2 from it-0 gram -> mu at it-1
    f32x4 D[4][4];

    for (int it = 0; it < ITERS; ++it) {
        const bool three = (it < ONE_LO) || (it >= ONE_HI);
        const bool g1    = !three || (it == ONE_HI);  // gram 1-pass (X exactly bf16)
        const bool xlo0  = (it == ONE_HI);            // xf.lo == 0 at it==ONE_HI
        const bool xlo_st = three && (it != ONE_LO - 1);  // next iter reads lo?
        float c1 = (it < GROW) ? 2.25f    : 1.5f;
        float c3 = (it < GROW) ? -1.6875f : -0.5f;
        if (it == 0) { c1 *= invF; c3 *= invF * invF * invF; }  // Frobenius fold
        if (it == 1) {
            // mu-scaling: lam_max(X1) <= f(min(mu,2/3)), f(x)=2.25x-1.6875x^3
            float s = s_acc;
#pragma unroll
            for (int m = 1; m < 64; m <<= 1) s += __shfl_xor(s, m, 64);
            const float mu = sqrtf(sqrtf(s)) * invF;
            const float xm = fminf(mu, 0.6666667f);
            const float fv = 2.25f * xm - 1.6875f * xm * xm * xm;
            const float im = 0.98f / fv;
            c1 *= im; c3 *= im * im * im;
        }
        c1 *= 0.5f; c3 *= 0.5f;   // W' = W/2 for the symmetrized double product

        // ---- gram: D = X^2 (exactly symmetric) ----
        zeroD(D);
#pragma unroll
        for (int S = 0; S < 2; ++S)
#pragma unroll
        for (int i = 0; i < 4; ++i)
#pragma unroll
        for (int j = 0; j < 4; ++j) {
            if (g1) D[i][j] = mfma_bf(xf[S][i].hi, xf[S][j].hi, D[i][j]);
            else    D[i][j] = mfma3 (xf[S][i],    xf[S][j],    D[i][j]);
        }
        if (it == 0) {
#pragma unroll
            for (int i = 0; i < 4; ++i)
#pragma unroll
            for (int j = 0; j < 4; ++j)
#pragma unroll
            for (int r = 0; r < 4; ++r) s_acc = fmaf(D[i][j][r], D[i][j][r], s_acc);
        }

        // ---- store W' = 0.5*(c1*I + c3*X^2), transposed (== W' by symmetry) ----
#pragma unroll
        for (int i = 0; i < 4; ++i)
#pragma unroll
        for (int j = 0; j < 4; ++j) {
            f32x4 v;
#pragma unroll
            for (int r = 0; r < 4; ++r) {
                v[r] = c3 * D[i][j][r];
                if (i == j && c == 4 * h4 + r) v[r] += c1;
            }
            stHL(Hhi, Hlo, three, c, h4, i, j, v);
        }

        // ---- mm2: D = X*W' + W'*X (symmetrized in-register) ----
        zeroD(D);
#pragma unroll
        for (int S = 0; S < 2; ++S) {
            Frag wf[4];
#pragma unroll
            for (int t = 0; t < 4; ++t) {
                wf[t].hi = rdP(Hhi, c, h4, t, S);
                wf[t].lo = three ? rdP(Hlo, c, h4, t, S) : short8{0,0,0,0,0,0,0,0};
            }
#pragma unroll
            for (int i = 0; i < 4; ++i)
#pragma unroll
            for (int j = 0; j < 4; ++j) {
                if (three) {
                    D[i][j] = mfma_bf(xf[S][i].hi, wf[j].hi, D[i][j]);
                    D[i][j] = mfma_bf(xf[S][i].hi, wf[j].lo, D[i][j]);
                    if (!xlo0) D[i][j] = mfma_bf(xf[S][i].lo, wf[j].hi, D[i][j]);
                    D[i][j] = mfma_bf(wf[i].hi, xf[S][j].hi, D[i][j]);
                    D[i][j] = mfma_bf(wf[i].lo, xf[S][j].hi, D[i][j]);
                    if (!xlo0) D[i][j] = mfma_bf(wf[i].hi, xf[S][j].lo, D[i][j]);
                } else {
                    D[i][j] = mfma_bf(xf[S][i].hi, wf[j].hi, D[i][j]);
                    D[i][j] = mfma_bf(wf[i].hi, xf[S][j].hi, D[i][j]);
                }
            }
        }

        // ---- store X_new (transposed), read back fragments ----
#pragma unroll
        for (int i = 0; i < 4; ++i)
#pragma unroll
        for (int j = 0; j < 4; ++j) stHL(Hhi, Hlo, xlo_st, c, h4, i, j, D[i][j]);
#pragma unroll
        for (int S = 0; S < 2; ++S)
#pragma unroll
        for (int t = 0; t < 4; ++t) {
            xf[S][t].hi = rdP(Hhi, c, h4, t, S);
            xf[S][t].lo = xlo_st ? rdP(Hlo, c, h4, t, S) : short8{0,0,0,0,0,0,0,0};
        }
    }
    // xf = frags of S = sign(B)

    // ---- validation: trace gate. tr(S^2 - I) from 1-pass gram diagonal.
    // Healthy: small negative (few unconverged tiny eigenvalues). Anomaly
    // (NaN / divergence / mass truncation) leaves (-4.5, 0.9). NaN-safe.
    zeroD(D);
#pragma unroll
    for (int S = 0; S < 2; ++S)
#pragma unroll
    for (int i = 0; i < 4; ++i)
#pragma unroll
    for (int j = 0; j < 4; ++j) D[i][j] = mfma_bf(xf[S][i].hi, xf[S][j].hi, D[i][j]);
    float trc = 0.f;
    if (h4 == (c >> 2)) {               // this lane holds diagonal elements
        const int r = c - 4 * h4;       // in [0,3]
#pragma unroll
        for (int i = 0; i < 4; ++i) trc += D[i][i][r];
    }
#pragma unroll
    for (int m = 1; m < 64; m <<= 1) trc += __shfl_xor(trc, m, 64);
    const float trdev = trc - 64.f;
    const bool bad = !(trdev > -4.5f && trdev < 0.9f);   // NaN -> flagged

    // ---- epilogue: D = B*S + S*B (symmetrized double product) ----
    zeroD(D);
#pragma unroll
    for (int S = 0; S < 2; ++S) {
        Frag b4[4];
#pragma unroll
        for (int t = 0; t < 4; ++t) {
            float e[8]; load_row8(src, c, h4, t, S, e); b4[t] = pack3(e);
        }
#pragma unroll
        for (int i = 0; i < 4; ++i)
#pragma unroll
        for (int j = 0; j < 4; ++j) {
            D[i][j] = mfma3(b4[i], xf[S][j], D[i][j]);
            D[i][j] = mfma3(xf[S][i], b4[j], D[i][j]);
        }
    }

    // out = 0.25*(BS+SB) + 0.5*B + eps*I
#pragma unroll
    for (int i = 0; i < 4; ++i)
#pragma unroll
    for (int j = 0; j < 4; ++j)
#pragma unroll
    for (int r = 0; r < 4; ++r) {
        const int p = 16 * i + 4 * h4 + r;
        const int q = 16 * j + c;
        const float bval = src[p * 64 + q] - ((p == q) ? EPS_ : 0.f);
        dst[p * 64 + q] = 0.25f * D[i][j][r] + 0.5f * bval + ((p == q) ? EPS_ : 0.f);
    }

    if (lane == 0) flags[mat] = bad ? 1 : 0;
}

// ------------------------ fp32 fallback (known good) ------------------------
constexpr int FB_LD = 68;

__device__ __forceinline__ void fb_mm64(const float* __restrict__ A,
                                        const float* __restrict__ Bm,
                                        int ti, int tj, float acc[4][4]) {
#pragma unroll
    for (int r = 0; r < 4; ++r)
#pragma unroll
        for (int cc = 0; cc < 4; ++cc) acc[r][cc] = 0.f;
#pragma unroll 4
    for (int k = 0; k < 64; ++k) {
        const float4 a = *reinterpret_cast<const float4*>(&A [k * FB_LD + 4 * ti]);
        const float4 b = *reinterpret_cast<const float4*>(&Bm[k * FB_LD + 4 * tj]);
        const float ar[4] = {a.x, a.y, a.z, a.w};
        const float br[4] = {b.x, b.y, b.z, b.w};
#pragma unroll
        for (int r = 0; r < 4; ++r)
#pragma unroll
            for (int cc = 0; cc < 4; ++cc)
                acc[r][cc] = fmaf(ar[r], br[cc], acc[r][cc]);
    }
}

__global__ __launch_bounds__(256) void reeig_fb(const float* __restrict__ in,
                                                float* __restrict__ out,
                                                const int* __restrict__ flags) {
    if (flags && flags[blockIdx.x] == 0) return;

    __shared__ __align__(16) float Bs[64 * FB_LD];
    __shared__ __align__(16) float Xs[64 * FB_LD];
    __shared__ __align__(16) float Ws[64 * FB_LD];
    __shared__ float red[4];

    const int tid = threadIdx.x;
    const int tj  = tid & 15;
    const int ti  = tid >> 4;
    const size_t base = (size_t)blockIdx.x * 4096;
    const float* __restrict__ src = in + base;
    float* __restrict__ dst = out + base;

    float4 v4[4];
    float frob = 0.f;
#pragma unroll
    for (int q = 0; q < 4; ++q) {
        const int idx4 = tid + 256 * q;
        const int lin  = idx4 << 2;
        const int r    = lin >> 6;
        const int c    = lin & 63;
        float4 v = reinterpret_cast<const float4*>(src)[idx4];
        const int d = r - c;
        v.x -= (d == 0) ? EPS_ : 0.f;
        v.y -= (d == 1) ? EPS_ : 0.f;
        v.z -= (d == 2) ? EPS_ : 0.f;
        v.w -= (d == 3) ? EPS_ : 0.f;
        v4[q] = v;
        frob += v.x * v.x + v.y * v.y + v.z * v.z + v.w * v.w;
        *reinterpret_cast<float4*>(&Bs[r * FB_LD + c]) = v;
    }
#pragma unroll
    for (int off = 32; off > 0; off >>= 1) frob += __shfl_down(frob, off);
    if ((tid & 63) == 0) red[tid >> 6] = frob;
    __syncthreads();
    const float tot = red[0] + red[1] + red[2] + red[3];
    const float inv = (tot > 0.f) ? rsqrtf(tot) : 0.f;

#pragma unroll
    for (int q = 0; q < 4; ++q) {
        const int idx4 = tid + 256 * q;
        const int lin  = idx4 << 2;
        const int r    = lin >> 6;
        const int c    = lin & 63;
        float4 v = v4[q];
        v.x *= inv; v.y *= inv; v.z *= inv; v.w *= inv;
        *reinterpret_cast<float4*>(&Xs[r * FB_LD + c]) = v;
    }
    __syncthreads();

    float acc[4][4];
    for (int it = 0; it < 14; ++it) {
        const bool  g  = (it < 9);
        const float c1 = g ? 2.25f    : 1.5f;
        const float c3 = g ? -1.6875f : -0.5f;

        fb_mm64(Xs, Xs, ti, tj, acc);
#pragma unroll
        for (int r = 0; r < 4; ++r) {
            const int i = 4 * ti + r;
            float4 w;
            w.x = c3 * acc[r][0] + ((i == 4 * tj + 0) ? c1 : 0.f);
            w.y = c3 * acc[r][1] + ((i == 4 * tj + 1) ? c1 : 0.f);
            w.z = c3 * acc[r][2] + ((i == 4 * tj + 2) ? c1 : 0.f);
            w.w = c3 * acc[r][3] + ((i == 4 * tj + 3) ? c1 : 0.f);
            *reinterpret_cast<float4*>(&Ws[i * FB_LD + 4 * tj]) = w;
        }
        __syncthreads();

        fb_mm64(Xs, Ws, ti, tj, acc);
        __syncthreads();
#pragma unroll
        for (int r = 0; r < 4; ++r) {
            const int i = 4 * ti + r;
            float4 x;
            x.x = acc[r][0]; x.y = acc[r][1]; x.z = acc[r][2]; x.w = acc[r][3];
            *reinterpret_cast<float4*>(&Xs[i * FB_LD + 4 * tj]) = x;
        }
        __syncthreads();
    }

    fb_mm64(Bs, Xs, ti, tj, acc);
#pragma unroll
    for (int r = 0; r < 4; ++r) {
        const int i = 4 * ti + r;
        float4 o;
        o.x = 0.5f * (acc[r][0] + Bs[i * FB_LD + 4 * tj + 0]) + ((i == 4 * tj + 0) ? EPS_ : 0.f);
        o.y = 0.5f * (acc[r][1] + Bs[i * FB_LD + 4 * tj + 1]) + ((i == 4 * tj + 1) ? EPS_ : 0.f);
        o.z = 0.5f * (acc[r][2] + Bs[i * FB_LD + 4 * tj + 2]) + ((i == 4 * tj + 2) ? EPS_ : 0.f);
        o.w = 0.5f * (acc[r][3] + Bs[i * FB_LD + 4 * tj + 3]) + ((i == 4 * tj + 3) ? EPS_ : 0.f);
        *reinterpret_cast<float4*>(&dst[i * 64 + 4 * tj]) = o;
    }
}

extern "C" void kernel_launch(void* const* d_in, const int* in_sizes, int n_in,
                              void* d_out, int out_size, void* d_ws, size_t ws_size,
                              hipStream_t stream) {
    const float* X = (const float*)d_in[0];
    float* O = (float*)d_out;
    const int nmat = in_sizes[0] / 4096;   // 8192
    if (ws_size >= (size_t)nmat * sizeof(int)) {
        int* flags = (int*)d_ws;
        reeig_mx<<<nmat / 4, 256, 0, stream>>>(X, O, flags);
        reeig_fb<<<nmat, 256, 0, stream>>>(X, O, flags);
    } else {
        reeig_fb<<<nmat, 256, 0, stream>>>(X, O, nullptr);
    }
}